// Round 6
// baseline (198.605 us; speedup 1.0000x reference)
//
#include <hip/hip_runtime.h>

#define B_    16
#define T_    4096
#define D_    1024
#define CD_   8
#define CS_   1024
#define NROWS 65536
#define EPSF  1e-12f

// ---- d_out float offsets (outputs concatenated flat in return order) ----
#define OUT_OFF    0           // [16,4096,1024] = 67108864
#define COMMIT_OFF 67108864    // [16]
#define CBLOSS_OFF 67108880    // [16]
#define IDX_OFF    67108896    // [16,4096] as float
#define ZE_OFF     67174432    // [16,4096,8]

// ---- ws float offsets ----
#define WS_INWT 0        // in_wT   [8][1024]  (c-major)
#define WS_CBR  8192     // cbn_row [1024][8]  (row-major normalized codebook)
#define WS_OUTW 16384    // out_w   [8][1024]  (c-major)
#define WS_CN2  24576    // ||cbn_j||^2 [1024]

// ---------------------------------------------------------------------------
// Prep, 24 blocks x 256 (unchanged from round 5, bit-exact)
// ---------------------------------------------------------------------------
__global__ __launch_bounds__(256)
void vq_prep(const float* __restrict__ in_v, const float* __restrict__ in_g,
             const float* __restrict__ out_v, const float* __restrict__ out_g,
             const float* __restrict__ cb, float* __restrict__ ws,
             float* __restrict__ dout) {
    int t = threadIdx.x;
    int blk = blockIdx.x;

    if (blk < 16) {
        __shared__ float s_norm[CD_];
        int lane = t & 63;
        int wid = t >> 6;     // 0..3
        #pragma unroll
        for (int half = 0; half < 2; ++half) {
            int c = wid + half * 4;
            float s = 0.f;
            #pragma unroll
            for (int i = 0; i < D_ / 64; ++i) {
                float v = in_v[(size_t)(lane + 64 * i) * CD_ + c];
                s = fmaf(v, v, s);
            }
            #pragma unroll
            for (int m = 1; m <= 32; m <<= 1) s += __shfl_xor(s, m, 64);
            if (lane == 0) s_norm[c] = sqrtf(s);
        }
        __syncthreads();

        #pragma unroll
        for (int rep = 0; rep < 2; ++rep) {
            int idx = blk * 512 + rep * 256 + t;
            int c = idx >> 10, d = idx & (D_ - 1);
            ws[WS_INWT + idx] = in_g[c] * in_v[(size_t)d * CD_ + c] / fmaxf(EPSF, s_norm[c]);
        }

        if (blk == 0 && t < 32) dout[COMMIT_OFF + t] = 0.f;
    } else if (blk < 20) {
        int j = (blk - 16) * 256 + t;
        float v[CD_]; float s = 0.f;
        #pragma unroll
        for (int c = 0; c < CD_; ++c) { v[c] = cb[j * CD_ + c]; s = fmaf(v[c], v[c], s); }
        float n = fmaxf(EPSF, sqrtf(s));
        float n2 = 0.f;
        #pragma unroll
        for (int c = 0; c < CD_; ++c) {
            float q = v[c] / n;
            ws[WS_CBR + j * CD_ + c] = q;
            n2 = fmaf(q, q, n2);
        }
        ws[WS_CN2 + j] = n2;
    } else {
        int d = (blk - 20) * 256 + t;
        float v[CD_]; float s = 0.f;
        #pragma unroll
        for (int c = 0; c < CD_; ++c) { v[c] = out_v[c * D_ + d]; s = fmaf(v[c], v[c], s); }
        float n = fmaxf(EPSF, sqrtf(s));
        float g = out_g[d];
        #pragma unroll
        for (int c = 0; c < CD_; ++c) ws[WS_OUTW + c * D_ + d] = g * v[c] / n;
    }
}

// ---------------------------------------------------------------------------
// Stage 1: z_e = z @ in_wT + in_b (unchanged from round 5, bit-exact)
// ---------------------------------------------------------------------------
__global__ __launch_bounds__(256)
void vq_ze(const float* __restrict__ z, const float* __restrict__ in_b,
           const float* __restrict__ ws, float* __restrict__ dout) {
    __shared__ float lds[CD_ * D_];  // in_wT, 32 KB
    int t = threadIdx.x;
    #pragma unroll
    for (int i = 0; i < 8; ++i)
        ((float4*)lds)[i * 256 + t] = ((const float4*)ws)[i * 256 + t];
    __syncthreads();

    int lane = t & 63;
    int wv = (blockIdx.x << 2) + (t >> 6);  // 0..8191

    float bia[CD_];
    #pragma unroll
    for (int c = 0; c < CD_; ++c) bia[c] = in_b[c];

    for (int it = 0; it < 4; ++it) {
        int bi = wv + (it << 13);   // 0..32767
        int row0 = bi << 1;         // 2 consecutive rows

        float ze[2][CD_];
        #pragma unroll
        for (int r = 0; r < 2; ++r)
            #pragma unroll
            for (int c = 0; c < CD_; ++c) ze[r][c] = 0.f;

        #pragma unroll
        for (int k = 0; k < 4; ++k) {
            float4 zv0 = *(const float4*)(z + (size_t)(row0)     * D_ + (k << 8) + (lane << 2));
            float4 zv1 = *(const float4*)(z + (size_t)(row0 + 1) * D_ + (k << 8) + (lane << 2));
            #pragma unroll
            for (int c = 0; c < CD_; ++c) {
                float4 w4 = *(const float4*)(lds + c * D_ + (k << 8) + (lane << 2));
                ze[0][c] = fmaf(zv0.x, w4.x, ze[0][c]);
                ze[0][c] = fmaf(zv0.y, w4.y, ze[0][c]);
                ze[0][c] = fmaf(zv0.z, w4.z, ze[0][c]);
                ze[0][c] = fmaf(zv0.w, w4.w, ze[0][c]);
                ze[1][c] = fmaf(zv1.x, w4.x, ze[1][c]);
                ze[1][c] = fmaf(zv1.y, w4.y, ze[1][c]);
                ze[1][c] = fmaf(zv1.z, w4.z, ze[1][c]);
                ze[1][c] = fmaf(zv1.w, w4.w, ze[1][c]);
            }
        }

        #pragma unroll
        for (int r = 0; r < 2; ++r) {
            #pragma unroll
            for (int c = 0; c < CD_; ++c) {
                float v = ze[r][c];
                v += __shfl_xor(v, 1, 64);
                v += __shfl_xor(v, 2, 64);
                v += __shfl_xor(v, 4, 64);
                v += __shfl_xor(v, 8, 64);
                v += __shfl_xor(v, 16, 64);
                v += __shfl_xor(v, 32, 64);
                ze[r][c] = v + bia[c];
            }
        }

        if (lane == 0) {
            *(float4*)(dout + ZE_OFF + (size_t)row0 * CD_) =
                make_float4(ze[0][0], ze[0][1], ze[0][2], ze[0][3]);
            *(float4*)(dout + ZE_OFF + (size_t)row0 * CD_ + 4) =
                make_float4(ze[0][4], ze[0][5], ze[0][6], ze[0][7]);
        }
        if (lane == 1) {
            *(float4*)(dout + ZE_OFF + (size_t)(row0 + 1) * CD_) =
                make_float4(ze[1][0], ze[1][1], ze[1][2], ze[1][3]);
            *(float4*)(dout + ZE_OFF + (size_t)(row0 + 1) * CD_ + 4) =
                make_float4(ze[1][4], ze[1][5], ze[1][6], ze[1][7]);
        }
    }
}

// ---------------------------------------------------------------------------
// Stage 2+3 fused: scan (bit-exact round-5 structure) then out projection
// (bit-exact round-5 vq_out math). Indices stay block-local in LDS.
// 2048 blocks x 256 threads; each block owns 32 rows.
// ---------------------------------------------------------------------------
__global__ __launch_bounds__(256)
void vq_scanout(const float* __restrict__ ze_in, const float* __restrict__ cb,
                const float* __restrict__ ws, const float* __restrict__ out_b,
                float* __restrict__ dout) {
    __shared__ float s_cb[CS_ * CD_];  // 32 KB
    __shared__ float s_c2[CS_];        // 4 KB
    __shared__ int   s_idx[32];
    __shared__ float s_loss[4];
    int t = threadIdx.x;
    #pragma unroll
    for (int i = 0; i < 8; ++i)
        ((float4*)s_cb)[i * 256 + t] = ((const float4*)(ws + WS_CBR))[i * 256 + t];
    ((float4*)s_c2)[t] = ((const float4*)(ws + WS_CN2))[t];
    __syncthreads();

    int lane = t & 63;
    int wid = t >> 6;
    int r = t >> 3;            // 0..31 local row
    int sub = t & 7;
    int base = blockIdx.x * 32;
    int row = base + r;

    // ---- scan ----
    {
        float4 a  = *(const float4*)(ze_in + (size_t)row * CD_);
        float4 b4 = *(const float4*)(ze_in + (size_t)row * CD_ + 4);

        float s = 0.f;
        s = fmaf(a.x, a.x, s);   s = fmaf(a.y, a.y, s);
        s = fmaf(a.z, a.z, s);   s = fmaf(a.w, a.w, s);
        s = fmaf(b4.x, b4.x, s); s = fmaf(b4.y, b4.y, s);
        s = fmaf(b4.z, b4.z, s); s = fmaf(b4.w, b4.w, s);
        float tw = 2.f / fmaxf(EPSF, sqrtf(s));

        float bs = -1e38f;
        int bj = 0;
        #pragma unroll 4
        for (int jj = 0; jj < 128; ++jj) {
            int j = (jj << 3) + sub;
            float4 ca  = ((const float4*)s_cb)[j * 2];
            float4 cbv = ((const float4*)s_cb)[j * 2 + 1];
            float dot = 0.f;
            dot = fmaf(ca.x,  a.x,  dot);
            dot = fmaf(ca.y,  a.y,  dot);
            dot = fmaf(ca.z,  a.z,  dot);
            dot = fmaf(ca.w,  a.w,  dot);
            dot = fmaf(cbv.x, b4.x, dot);
            dot = fmaf(cbv.y, b4.y, dot);
            dot = fmaf(cbv.z, b4.z, dot);
            dot = fmaf(cbv.w, b4.w, dot);
            float sc = fmaf(dot, tw, -s_c2[j]);
            if (sc > bs || (sc == bs && j < bj)) { bs = sc; bj = j; }
        }
        #pragma unroll
        for (int m = 1; m <= 4; m <<= 1) {
            float os = __shfl_xor(bs, m, 64);
            int   oj = __shfl_xor(bj, m, 64);
            bool take = (os > bs) || (os == bs && oj < bj);
            bs = take ? os : bs;
            bj = take ? oj : bj;
        }

        float lsum = 0.f;
        if (sub == 0) {
            const float* q = cb + (size_t)bj * CD_;
            float d0 = a.x  - q[0]; lsum = fmaf(d0, d0, lsum);
            float d1 = a.y  - q[1]; lsum = fmaf(d1, d1, lsum);
            float d2 = a.z  - q[2]; lsum = fmaf(d2, d2, lsum);
            float d3 = a.w  - q[3]; lsum = fmaf(d3, d3, lsum);
            float d4 = b4.x - q[4]; lsum = fmaf(d4, d4, lsum);
            float d5 = b4.y - q[5]; lsum = fmaf(d5, d5, lsum);
            float d6 = b4.z - q[6]; lsum = fmaf(d6, d6, lsum);
            float d7 = b4.w - q[7]; lsum = fmaf(d7, d7, lsum);
        }
        lsum += __shfl_xor(lsum, 1, 64);
        lsum += __shfl_xor(lsum, 2, 64);
        lsum += __shfl_xor(lsum, 4, 64);
        lsum += __shfl_xor(lsum, 8, 64);
        lsum += __shfl_xor(lsum, 16, 64);
        lsum += __shfl_xor(lsum, 32, 64);
        if (lane == 0) s_loss[wid] = lsum;

        if (sub == 0) {
            dout[IDX_OFF + row] = (float)bj;
            s_idx[r] = bj;
        }
    }
    __syncthreads();
    if (t == 0) {
        float tot = s_loss[0] + s_loss[1] + s_loss[2] + s_loss[3];
        float v = tot * (1.f / 32768.f);
        int bt = row >> 12;
        atomicAdd(dout + COMMIT_OFF + bt, v);
        atomicAdd(dout + CBLOSS_OFF + bt, v);
    }

    // ---- out projection: wave wid handles rows base + wid*8 .. +7 ----
    const float* ow = ws + WS_OUTW;
    float4 ob[4];
    #pragma unroll
    for (int k = 0; k < 4; ++k)
        ob[k] = *(const float4*)(out_b + (k << 8) + (lane << 2));

    #pragma unroll
    for (int itr = 0; itr < 2; ++itr) {
        int lr0 = wid * 8 + itr * 4;
        int row0 = base + lr0;

        float zq[4][CD_];
        #pragma unroll
        for (int rr = 0; rr < 4; ++rr) {
            int j = s_idx[lr0 + rr];
            #pragma unroll
            for (int c = 0; c < CD_; ++c) zq[rr][c] = cb[j * CD_ + c];
        }

        #pragma unroll
        for (int k = 0; k < 4; ++k) {
            float4 a0 = ob[k], a1 = ob[k], a2 = ob[k], a3 = ob[k];
            #pragma unroll
            for (int c = 0; c < CD_; ++c) {
                float4 w4 = *(const float4*)(ow + c * D_ + (k << 8) + (lane << 2));
                a0.x = fmaf(zq[0][c], w4.x, a0.x); a0.y = fmaf(zq[0][c], w4.y, a0.y);
                a0.z = fmaf(zq[0][c], w4.z, a0.z); a0.w = fmaf(zq[0][c], w4.w, a0.w);
                a1.x = fmaf(zq[1][c], w4.x, a1.x); a1.y = fmaf(zq[1][c], w4.y, a1.y);
                a1.z = fmaf(zq[1][c], w4.z, a1.z); a1.w = fmaf(zq[1][c], w4.w, a1.w);
                a2.x = fmaf(zq[2][c], w4.x, a2.x); a2.y = fmaf(zq[2][c], w4.y, a2.y);
                a2.z = fmaf(zq[2][c], w4.z, a2.z); a2.w = fmaf(zq[2][c], w4.w, a2.w);
                a3.x = fmaf(zq[3][c], w4.x, a3.x); a3.y = fmaf(zq[3][c], w4.y, a3.y);
                a3.z = fmaf(zq[3][c], w4.z, a3.z); a3.w = fmaf(zq[3][c], w4.w, a3.w);
            }
            size_t obase = (size_t)row0 * D_ + (k << 8) + (lane << 2);
            *(float4*)(dout + OUT_OFF + obase)          = a0;
            *(float4*)(dout + OUT_OFF + obase + D_)     = a1;
            *(float4*)(dout + OUT_OFF + obase + 2 * D_) = a2;
            *(float4*)(dout + OUT_OFF + obase + 3 * D_) = a3;
        }
    }
}

extern "C" void kernel_launch(void* const* d_in, const int* in_sizes, int n_in,
                              void* d_out, int out_size, void* d_ws, size_t ws_size,
                              hipStream_t stream) {
    const float* z     = (const float*)d_in[0];
    const float* in_v  = (const float*)d_in[1];
    const float* in_g  = (const float*)d_in[2];
    const float* in_b  = (const float*)d_in[3];
    const float* out_v = (const float*)d_in[4];
    const float* out_g = (const float*)d_in[5];
    const float* out_b = (const float*)d_in[6];
    const float* cb    = (const float*)d_in[7];
    float* dout = (float*)d_out;
    float* ws   = (float*)d_ws;

    vq_prep<<<24, 256, 0, stream>>>(in_v, in_g, out_v, out_g, cb, ws, dout);
    vq_ze<<<2048, 256, 0, stream>>>(z, in_b, ws, dout);
    vq_scanout<<<2048, 256, 0, stream>>>(dout + ZE_OFF, cb, ws, out_b, dout);
}

// Round 7
// 191.747 us; speedup vs baseline: 1.0358x; 1.0358x over previous
//
#include <hip/hip_runtime.h>

#define B_    16
#define T_    4096
#define D_    1024
#define CD_   8
#define CS_   1024
#define NROWS 65536
#define EPSF  1e-12f

// ---- d_out float offsets (outputs concatenated flat in return order) ----
#define OUT_OFF    0           // [16,4096,1024] = 67108864
#define COMMIT_OFF 67108864    // [16]
#define CBLOSS_OFF 67108880    // [16]
#define IDX_OFF    67108896    // [16,4096] as float
#define ZE_OFF     67174432    // [16,4096,8]

// ---- ws float offsets ----
#define WS_INWT 0        // in_wT    [8][1024]      (c-major)
#define WS_CBF2 8192     // cbnT2    [4][1024][2]   (float2 planes, pair (2cp,2cp+1))
#define WS_OUTW 16384    // out_w    [8][1024]      (c-major)
#define WS_CN2  24576    // ||cbn_j||^2 [1024]
#define WS_IDX  25600    // indices as int [65536]

// ---------------------------------------------------------------------------
// Prep, 24 blocks x 256. Same fp sequences as round 5; codebook now stored
// as float2 planes for the fused scan (same float values, new layout).
// ---------------------------------------------------------------------------
__global__ __launch_bounds__(256)
void vq_prep(const float* __restrict__ in_v, const float* __restrict__ in_g,
             const float* __restrict__ out_v, const float* __restrict__ out_g,
             const float* __restrict__ cb, float* __restrict__ ws,
             float* __restrict__ dout) {
    int t = threadIdx.x;
    int blk = blockIdx.x;

    if (blk < 16) {
        __shared__ float s_norm[CD_];
        int lane = t & 63;
        int wid = t >> 6;     // 0..3
        #pragma unroll
        for (int half = 0; half < 2; ++half) {
            int c = wid + half * 4;
            float s = 0.f;
            #pragma unroll
            for (int i = 0; i < D_ / 64; ++i) {
                float v = in_v[(size_t)(lane + 64 * i) * CD_ + c];
                s = fmaf(v, v, s);
            }
            #pragma unroll
            for (int m = 1; m <= 32; m <<= 1) s += __shfl_xor(s, m, 64);
            if (lane == 0) s_norm[c] = sqrtf(s);
        }
        __syncthreads();

        #pragma unroll
        for (int rep = 0; rep < 2; ++rep) {
            int idx = blk * 512 + rep * 256 + t;
            int c = idx >> 10, d = idx & (D_ - 1);
            ws[WS_INWT + idx] = in_g[c] * in_v[(size_t)d * CD_ + c] / fmaxf(EPSF, s_norm[c]);
        }

        if (blk == 0 && t < 32) dout[COMMIT_OFF + t] = 0.f;
    } else if (blk < 20) {
        int j = (blk - 16) * 256 + t;
        float v[CD_]; float s = 0.f;
        #pragma unroll
        for (int c = 0; c < CD_; ++c) { v[c] = cb[j * CD_ + c]; s = fmaf(v[c], v[c], s); }
        float n = fmaxf(EPSF, sqrtf(s));
        float n2 = 0.f;
        #pragma unroll
        for (int c = 0; c < CD_; ++c) {
            float q = v[c] / n;
            ws[WS_CBF2 + (((c >> 1) * CS_ + j) << 1) + (c & 1)] = q;
            n2 = fmaf(q, q, n2);
        }
        ws[WS_CN2 + j] = n2;
    } else {
        int d = (blk - 20) * 256 + t;
        float v[CD_]; float s = 0.f;
        #pragma unroll
        for (int c = 0; c < CD_; ++c) { v[c] = out_v[c * D_ + d]; s = fmaf(v[c], v[c], s); }
        float n = fmaxf(EPSF, sqrtf(s));
        float g = out_g[d];
        #pragma unroll
        for (int c = 0; c < CD_; ++c) ws[WS_OUTW + c * D_ + d] = g * v[c] / n;
    }
}

// ---------------------------------------------------------------------------
// Fused stage 1+2: z_e GEMV (bit-identical) -> in-register codebook scan.
// 1024 blocks x 512 thr; LDS = in_wT (32 KB) + cbnT2 (32 KB) = exactly 64 KB.
// cn2 lives in 16 registers/lane (j = lane + 64*m). Scores bit-identical to
// round 5; argmax policy (strict >, tie -> smaller j) is order-independent.
// ---------------------------------------------------------------------------
__global__ __launch_bounds__(512)
void vq_zescan(const float* __restrict__ z, const float* __restrict__ in_b,
               const float* __restrict__ cb, const float* __restrict__ ws,
               float* __restrict__ dout, int* __restrict__ idx_out) {
    __shared__ float lds[16384];   // [0,8192)=in_wT  [8192,16384)=cbnT2  (64 KB)
    int t = threadIdx.x;
    #pragma unroll
    for (int i = 0; i < 8; ++i)
        ((float4*)lds)[i * 512 + t] = ((const float4*)ws)[i * 512 + t];
    __syncthreads();

    int lane = t & 63;
    int wid = t >> 6;                       // 0..7
    int wv = (blockIdx.x << 3) + wid;       // 0..8191

    float bia[CD_];
    #pragma unroll
    for (int c = 0; c < CD_; ++c) bia[c] = in_b[c];

    float cn2r[16];
    #pragma unroll
    for (int m = 0; m < 16; ++m) cn2r[m] = ws[WS_CN2 + (m << 6) + lane];

    const float2* lds_f2 = (const float2*)(lds + 8192);
    float lsumIt[4];

    #pragma unroll
    for (int it = 0; it < 4; ++it) {
        int bi = wv + (it << 13);   // 0..32767
        int row0 = bi << 1;         // 2 consecutive rows

        // ---- z_e GEMV (identical fp sequence) ----
        float ze[2][CD_];
        #pragma unroll
        for (int r = 0; r < 2; ++r)
            #pragma unroll
            for (int c = 0; c < CD_; ++c) ze[r][c] = 0.f;

        #pragma unroll
        for (int k = 0; k < 4; ++k) {
            float4 zv0 = *(const float4*)(z + (size_t)(row0)     * D_ + (k << 8) + (lane << 2));
            float4 zv1 = *(const float4*)(z + (size_t)(row0 + 1) * D_ + (k << 8) + (lane << 2));
            #pragma unroll
            for (int c = 0; c < CD_; ++c) {
                float4 w4 = *(const float4*)(lds + c * D_ + (k << 8) + (lane << 2));
                ze[0][c] = fmaf(zv0.x, w4.x, ze[0][c]);
                ze[0][c] = fmaf(zv0.y, w4.y, ze[0][c]);
                ze[0][c] = fmaf(zv0.z, w4.z, ze[0][c]);
                ze[0][c] = fmaf(zv0.w, w4.w, ze[0][c]);
                ze[1][c] = fmaf(zv1.x, w4.x, ze[1][c]);
                ze[1][c] = fmaf(zv1.y, w4.y, ze[1][c]);
                ze[1][c] = fmaf(zv1.z, w4.z, ze[1][c]);
                ze[1][c] = fmaf(zv1.w, w4.w, ze[1][c]);
            }
        }

        #pragma unroll
        for (int r = 0; r < 2; ++r) {
            #pragma unroll
            for (int c = 0; c < CD_; ++c) {
                float v = ze[r][c];
                v += __shfl_xor(v, 1, 64);
                v += __shfl_xor(v, 2, 64);
                v += __shfl_xor(v, 4, 64);
                v += __shfl_xor(v, 8, 64);
                v += __shfl_xor(v, 16, 64);
                v += __shfl_xor(v, 32, 64);
                ze[r][c] = v + bia[c];
            }
        }

        // ---- write z_e (same as round 5) ----
        if (lane == 0) {
            *(float4*)(dout + ZE_OFF + (size_t)row0 * CD_) =
                make_float4(ze[0][0], ze[0][1], ze[0][2], ze[0][3]);
            *(float4*)(dout + ZE_OFF + (size_t)row0 * CD_ + 4) =
                make_float4(ze[0][4], ze[0][5], ze[0][6], ze[0][7]);
        }
        if (lane == 1) {
            *(float4*)(dout + ZE_OFF + (size_t)(row0 + 1) * CD_) =
                make_float4(ze[1][0], ze[1][1], ze[1][2], ze[1][3]);
            *(float4*)(dout + ZE_OFF + (size_t)(row0 + 1) * CD_ + 4) =
                make_float4(ze[1][4], ze[1][5], ze[1][6], ze[1][7]);
        }

        // ---- row norms (same fp sequence as the scan kernel) ----
        float tw[2];
        #pragma unroll
        for (int r = 0; r < 2; ++r) {
            float s = 0.f;
            #pragma unroll
            for (int c = 0; c < CD_; ++c) s = fmaf(ze[r][c], ze[r][c], s);
            tw[r] = 2.f / fmaxf(EPSF, sqrtf(s));
        }

        // ---- scan: lane handles codes j = lane + 64*m ----
        float bs[2] = {-1e38f, -1e38f};
        int   bj[2] = {0, 0};
        #pragma unroll 4
        for (int m = 0; m < 16; ++m) {
            int j = (m << 6) + lane;
            float2 v0 = lds_f2[j];
            float2 v1 = lds_f2[CS_ + j];
            float2 v2 = lds_f2[2 * CS_ + j];
            float2 v3 = lds_f2[3 * CS_ + j];
            #pragma unroll
            for (int r = 0; r < 2; ++r) {
                float dot = 0.f;
                dot = fmaf(v0.x, ze[r][0], dot);
                dot = fmaf(v0.y, ze[r][1], dot);
                dot = fmaf(v1.x, ze[r][2], dot);
                dot = fmaf(v1.y, ze[r][3], dot);
                dot = fmaf(v2.x, ze[r][4], dot);
                dot = fmaf(v2.y, ze[r][5], dot);
                dot = fmaf(v3.x, ze[r][6], dot);
                dot = fmaf(v3.y, ze[r][7], dot);
                float sc = fmaf(dot, tw[r], -cn2r[m]);
                if (sc > bs[r] || (sc == bs[r] && j < bj[r])) { bs[r] = sc; bj[r] = j; }
            }
        }

        // ---- cross-lane argmax (first-max tie policy, order-independent) ----
        #pragma unroll
        for (int r = 0; r < 2; ++r) {
            #pragma unroll
            for (int mlog = 0; mlog < 6; ++mlog) {
                int mk = 1 << mlog;
                float os = __shfl_xor(bs[r], mk, 64);
                int   oj = __shfl_xor(bj[r], mk, 64);
                bool take = (os > bs[r]) || (os == bs[r] && oj < bj[r]);
                bs[r] = take ? os : bs[r];
                bj[r] = take ? oj : bj[r];
            }
        }

        // ---- indices ----
        if (lane == 0) {
            dout[IDX_OFF + row0] = (float)bj[0];
            idx_out[row0] = bj[0];
        }
        if (lane == 1) {
            dout[IDX_OFF + row0 + 1] = (float)bj[1];
            idx_out[row0 + 1] = bj[1];
        }

        // ---- losses: lane 0 -> row0, lane 1 -> row1, butterfly-summed ----
        float lsum = 0.f;
        if (lane < 2) {
            int rr = lane;
            const float* q = cb + (size_t)bj[rr] * CD_;
            float d0 = ze[rr][0] - q[0]; lsum = fmaf(d0, d0, lsum);
            float d1 = ze[rr][1] - q[1]; lsum = fmaf(d1, d1, lsum);
            float d2 = ze[rr][2] - q[2]; lsum = fmaf(d2, d2, lsum);
            float d3 = ze[rr][3] - q[3]; lsum = fmaf(d3, d3, lsum);
            float d4 = ze[rr][4] - q[4]; lsum = fmaf(d4, d4, lsum);
            float d5 = ze[rr][5] - q[5]; lsum = fmaf(d5, d5, lsum);
            float d6 = ze[rr][6] - q[6]; lsum = fmaf(d6, d6, lsum);
            float d7 = ze[rr][7] - q[7]; lsum = fmaf(d7, d7, lsum);
        }
        lsum += __shfl_xor(lsum, 1, 64);
        lsum += __shfl_xor(lsum, 2, 64);
        lsum += __shfl_xor(lsum, 4, 64);
        lsum += __shfl_xor(lsum, 8, 64);
        lsum += __shfl_xor(lsum, 16, 64);
        lsum += __shfl_xor(lsum, 32, 64);
        lsumIt[it] = lsum;
    }

    // ---- per-block loss reduction (reuse lds[0..31] after a barrier) ----
    __syncthreads();
    if (lane == 0) {
        #pragma unroll
        for (int it = 0; it < 4; ++it) lds[it * 8 + wid] = lsumIt[it];
    }
    __syncthreads();
    if (t < 4) {
        float tot = 0.f;
        #pragma unroll
        for (int w = 0; w < 8; ++w) tot += lds[t * 8 + w];
        float v = tot * (1.f / 32768.f);
        int row_first = blockIdx.x * 16 + (t << 14);
        int bt = row_first >> 12;
        atomicAdd(dout + COMMIT_OFF + bt, v);
        atomicAdd(dout + CBLOSS_OFF + bt, v);
    }
}

// ---------------------------------------------------------------------------
// Out projection: out = codebook[idx] @ out_w + out_b (unchanged, bit-exact)
// ---------------------------------------------------------------------------
__global__ __launch_bounds__(256)
void vq_out(const float* __restrict__ cb, const float* __restrict__ ws,
            const float* __restrict__ out_b, const int* __restrict__ idx,
            float* __restrict__ out) {
    int t = threadIdx.x;
    int lane = t & 63;
    int wv = (blockIdx.x << 2) + (t >> 6);  // 0..4095
    const float* ow = ws + WS_OUTW;

    float4 ob[4];
    #pragma unroll
    for (int k = 0; k < 4; ++k)
        ob[k] = *(const float4*)(out_b + (k << 8) + (lane << 2));

    for (int it = 0; it < 4; ++it) {
        int bi = wv + (it << 12);
        int row0 = bi << 2;

        float zq[4][CD_];
        #pragma unroll
        for (int r = 0; r < 4; ++r) {
            int j = idx[row0 + r];
            #pragma unroll
            for (int c = 0; c < CD_; ++c) zq[r][c] = cb[j * CD_ + c];
        }

        #pragma unroll
        for (int k = 0; k < 4; ++k) {
            float4 a0 = ob[k], a1 = ob[k], a2 = ob[k], a3 = ob[k];
            #pragma unroll
            for (int c = 0; c < CD_; ++c) {
                float4 w4 = *(const float4*)(ow + c * D_ + (k << 8) + (lane << 2));
                a0.x = fmaf(zq[0][c], w4.x, a0.x); a0.y = fmaf(zq[0][c], w4.y, a0.y);
                a0.z = fmaf(zq[0][c], w4.z, a0.z); a0.w = fmaf(zq[0][c], w4.w, a0.w);
                a1.x = fmaf(zq[1][c], w4.x, a1.x); a1.y = fmaf(zq[1][c], w4.y, a1.y);
                a1.z = fmaf(zq[1][c], w4.z, a1.z); a1.w = fmaf(zq[1][c], w4.w, a1.w);
                a2.x = fmaf(zq[2][c], w4.x, a2.x); a2.y = fmaf(zq[2][c], w4.y, a2.y);
                a2.z = fmaf(zq[2][c], w4.z, a2.z); a2.w = fmaf(zq[2][c], w4.w, a2.w);
                a3.x = fmaf(zq[3][c], w4.x, a3.x); a3.y = fmaf(zq[3][c], w4.y, a3.y);
                a3.z = fmaf(zq[3][c], w4.z, a3.z); a3.w = fmaf(zq[3][c], w4.w, a3.w);
            }
            size_t base = (size_t)row0 * D_ + (k << 8) + (lane << 2);
            *(float4*)(out + base)            = a0;
            *(float4*)(out + base + D_)       = a1;
            *(float4*)(out + base + 2 * D_)   = a2;
            *(float4*)(out + base + 3 * D_)   = a3;
        }
    }
}

extern "C" void kernel_launch(void* const* d_in, const int* in_sizes, int n_in,
                              void* d_out, int out_size, void* d_ws, size_t ws_size,
                              hipStream_t stream) {
    const float* z     = (const float*)d_in[0];
    const float* in_v  = (const float*)d_in[1];
    const float* in_g  = (const float*)d_in[2];
    const float* in_b  = (const float*)d_in[3];
    const float* out_v = (const float*)d_in[4];
    const float* out_g = (const float*)d_in[5];
    const float* out_b = (const float*)d_in[6];
    const float* cb    = (const float*)d_in[7];
    float* dout = (float*)d_out;
    float* ws   = (float*)d_ws;
    int* idxp   = (int*)(ws + WS_IDX);

    vq_prep<<<24, 256, 0, stream>>>(in_v, in_g, out_v, out_g, cb, ws, dout);
    vq_zescan<<<1024, 512, 0, stream>>>(z, in_b, cb, ws, dout, idxp);
    vq_out<<<1024, 256, 0, stream>>>(cb, ws, out_b, idxp, dout + OUT_OFF);
}

// Round 8
// 182.373 us; speedup vs baseline: 1.0890x; 1.0514x over previous
//
#include <hip/hip_runtime.h>

#define B_    16
#define T_    4096
#define D_    1024
#define CD_   8
#define CS_   1024
#define NROWS 65536
#define EPSF  1e-12f

// ---- d_out float offsets (outputs concatenated flat in return order) ----
#define OUT_OFF    0           // [16,4096,1024] = 67108864
#define COMMIT_OFF 67108864    // [16]
#define CBLOSS_OFF 67108880    // [16]
#define IDX_OFF    67108896    // [16,4096] as float
#define ZE_OFF     67174432    // [16,4096,8]

// ---- ws float offsets ----
#define WS_INWT 0        // in_wT   [8][1024]  (c-major)
#define WS_CBR  8192     // cbn_row [1024][8]  (row-major normalized codebook)
#define WS_OUTW 16384    // out_w   [8][1024]  (c-major)
#define WS_CN2  24576    // ||cbn_j||^2 [1024]
#define WS_IDX  25600    // indices as int [65536]

// ---------------------------------------------------------------------------
// Prep, 24 blocks x 256 (round-5 verbatim, bit-exact)
// ---------------------------------------------------------------------------
__global__ __launch_bounds__(256)
void vq_prep(const float* __restrict__ in_v, const float* __restrict__ in_g,
             const float* __restrict__ out_v, const float* __restrict__ out_g,
             const float* __restrict__ cb, float* __restrict__ ws,
             float* __restrict__ dout) {
    int t = threadIdx.x;
    int blk = blockIdx.x;

    if (blk < 16) {
        __shared__ float s_norm[CD_];
        int lane = t & 63;
        int wid = t >> 6;     // 0..3
        #pragma unroll
        for (int half = 0; half < 2; ++half) {
            int c = wid + half * 4;
            float s = 0.f;
            #pragma unroll
            for (int i = 0; i < D_ / 64; ++i) {
                float v = in_v[(size_t)(lane + 64 * i) * CD_ + c];
                s = fmaf(v, v, s);
            }
            #pragma unroll
            for (int m = 1; m <= 32; m <<= 1) s += __shfl_xor(s, m, 64);
            if (lane == 0) s_norm[c] = sqrtf(s);
        }
        __syncthreads();

        #pragma unroll
        for (int rep = 0; rep < 2; ++rep) {
            int idx = blk * 512 + rep * 256 + t;
            int c = idx >> 10, d = idx & (D_ - 1);
            ws[WS_INWT + idx] = in_g[c] * in_v[(size_t)d * CD_ + c] / fmaxf(EPSF, s_norm[c]);
        }

        if (blk == 0 && t < 32) dout[COMMIT_OFF + t] = 0.f;
    } else if (blk < 20) {
        int j = (blk - 16) * 256 + t;
        float v[CD_]; float s = 0.f;
        #pragma unroll
        for (int c = 0; c < CD_; ++c) { v[c] = cb[j * CD_ + c]; s = fmaf(v[c], v[c], s); }
        float n = fmaxf(EPSF, sqrtf(s));
        float n2 = 0.f;
        #pragma unroll
        for (int c = 0; c < CD_; ++c) {
            float q = v[c] / n;
            ws[WS_CBR + j * CD_ + c] = q;
            n2 = fmaf(q, q, n2);
        }
        ws[WS_CN2 + j] = n2;
    } else {
        int d = (blk - 20) * 256 + t;
        float v[CD_]; float s = 0.f;
        #pragma unroll
        for (int c = 0; c < CD_; ++c) { v[c] = out_v[c * D_ + d]; s = fmaf(v[c], v[c], s); }
        float n = fmaxf(EPSF, sqrtf(s));
        float g = out_g[d];
        #pragma unroll
        for (int c = 0; c < CD_; ++c) ws[WS_OUTW + c * D_ + d] = g * v[c] / n;
    }
}

// ---------------------------------------------------------------------------
// Stage 1: z_e = z @ in_wT + in_b. 4 rows per wave-iteration (2 iterations),
// no scan state -> fits registers; loads for 4 rows give 16 KB MLP per wave.
// FP sequence per row identical to round 5 (bit-exact z_e).
// ---------------------------------------------------------------------------
__global__ __launch_bounds__(256)
void vq_ze(const float* __restrict__ z, const float* __restrict__ in_b,
           const float* __restrict__ ws, float* __restrict__ dout) {
    __shared__ float lds[CD_ * D_];  // in_wT, 32 KB
    int t = threadIdx.x;
    #pragma unroll
    for (int i = 0; i < 8; ++i)
        ((float4*)lds)[i * 256 + t] = ((const float4*)ws)[i * 256 + t];
    __syncthreads();

    int lane = t & 63;
    int wv = (blockIdx.x << 2) + (t >> 6);  // 0..8191

    float bia[CD_];
    #pragma unroll
    for (int c = 0; c < CD_; ++c) bia[c] = in_b[c];

    #pragma unroll
    for (int it = 0; it < 2; ++it) {
        int bi = wv + (it << 13);   // 0..16383
        int row0 = bi << 2;         // 4 consecutive rows, same batch b

        float ze[4][CD_];
        #pragma unroll
        for (int r = 0; r < 4; ++r)
            #pragma unroll
            for (int c = 0; c < CD_; ++c) ze[r][c] = 0.f;

        #pragma unroll
        for (int k = 0; k < 4; ++k) {
            float4 zv0 = *(const float4*)(z + (size_t)(row0)     * D_ + (k << 8) + (lane << 2));
            float4 zv1 = *(const float4*)(z + (size_t)(row0 + 1) * D_ + (k << 8) + (lane << 2));
            float4 zv2 = *(const float4*)(z + (size_t)(row0 + 2) * D_ + (k << 8) + (lane << 2));
            float4 zv3 = *(const float4*)(z + (size_t)(row0 + 3) * D_ + (k << 8) + (lane << 2));
            #pragma unroll
            for (int c = 0; c < CD_; ++c) {
                float4 w4 = *(const float4*)(lds + c * D_ + (k << 8) + (lane << 2));
                ze[0][c] = fmaf(zv0.x, w4.x, ze[0][c]);
                ze[0][c] = fmaf(zv0.y, w4.y, ze[0][c]);
                ze[0][c] = fmaf(zv0.z, w4.z, ze[0][c]);
                ze[0][c] = fmaf(zv0.w, w4.w, ze[0][c]);
                ze[1][c] = fmaf(zv1.x, w4.x, ze[1][c]);
                ze[1][c] = fmaf(zv1.y, w4.y, ze[1][c]);
                ze[1][c] = fmaf(zv1.z, w4.z, ze[1][c]);
                ze[1][c] = fmaf(zv1.w, w4.w, ze[1][c]);
                ze[2][c] = fmaf(zv2.x, w4.x, ze[2][c]);
                ze[2][c] = fmaf(zv2.y, w4.y, ze[2][c]);
                ze[2][c] = fmaf(zv2.z, w4.z, ze[2][c]);
                ze[2][c] = fmaf(zv2.w, w4.w, ze[2][c]);
                ze[3][c] = fmaf(zv3.x, w4.x, ze[3][c]);
                ze[3][c] = fmaf(zv3.y, w4.y, ze[3][c]);
                ze[3][c] = fmaf(zv3.z, w4.z, ze[3][c]);
                ze[3][c] = fmaf(zv3.w, w4.w, ze[3][c]);
            }
        }

        #pragma unroll
        for (int r = 0; r < 4; ++r) {
            #pragma unroll
            for (int c = 0; c < CD_; ++c) {
                float v = ze[r][c];
                v += __shfl_xor(v, 1, 64);
                v += __shfl_xor(v, 2, 64);
                v += __shfl_xor(v, 4, 64);
                v += __shfl_xor(v, 8, 64);
                v += __shfl_xor(v, 16, 64);
                v += __shfl_xor(v, 32, 64);
                ze[r][c] = v + bia[c];
            }
        }

        if (lane == 0) {
            *(float4*)(dout + ZE_OFF + (size_t)row0 * CD_) =
                make_float4(ze[0][0], ze[0][1], ze[0][2], ze[0][3]);
            *(float4*)(dout + ZE_OFF + (size_t)row0 * CD_ + 4) =
                make_float4(ze[0][4], ze[0][5], ze[0][6], ze[0][7]);
        }
        if (lane == 1) {
            *(float4*)(dout + ZE_OFF + (size_t)(row0 + 1) * CD_) =
                make_float4(ze[1][0], ze[1][1], ze[1][2], ze[1][3]);
            *(float4*)(dout + ZE_OFF + (size_t)(row0 + 1) * CD_ + 4) =
                make_float4(ze[1][4], ze[1][5], ze[1][6], ze[1][7]);
        }
        if (lane == 2) {
            *(float4*)(dout + ZE_OFF + (size_t)(row0 + 2) * CD_) =
                make_float4(ze[2][0], ze[2][1], ze[2][2], ze[2][3]);
            *(float4*)(dout + ZE_OFF + (size_t)(row0 + 2) * CD_ + 4) =
                make_float4(ze[2][4], ze[2][5], ze[2][6], ze[2][7]);
        }
        if (lane == 3) {
            *(float4*)(dout + ZE_OFF + (size_t)(row0 + 3) * CD_) =
                make_float4(ze[3][0], ze[3][1], ze[3][2], ze[3][3]);
            *(float4*)(dout + ZE_OFF + (size_t)(row0 + 3) * CD_ + 4) =
                make_float4(ze[3][4], ze[3][5], ze[3][6], ze[3][7]);
        }
    }
}

// ---------------------------------------------------------------------------
// Stage 2: scan (round-5 verbatim, bit-exact). 2048 blocks x 256.
// ---------------------------------------------------------------------------
__global__ __launch_bounds__(256)
void vq_scan(const float* __restrict__ ze_in, const float* __restrict__ cb,
             const float* __restrict__ ws, float* __restrict__ dout,
             int* __restrict__ idx_out) {
    __shared__ float s_cb[CS_ * CD_];  // 32 KB
    __shared__ float s_c2[CS_];        // 4 KB
    __shared__ float s_loss[4];
    int t = threadIdx.x;
    #pragma unroll
    for (int i = 0; i < 8; ++i)
        ((float4*)s_cb)[i * 256 + t] = ((const float4*)(ws + WS_CBR))[i * 256 + t];
    ((float4*)s_c2)[t] = ((const float4*)(ws + WS_CN2))[t];
    __syncthreads();

    int lane = t & 63;
    int wid = t >> 6;
    int r = t >> 3;            // 0..31 local row
    int sub = t & 7;
    int row = blockIdx.x * 32 + r;

    float4 a  = *(const float4*)(ze_in + (size_t)row * CD_);
    float4 b4 = *(const float4*)(ze_in + (size_t)row * CD_ + 4);

    float s = 0.f;
    s = fmaf(a.x, a.x, s);   s = fmaf(a.y, a.y, s);
    s = fmaf(a.z, a.z, s);   s = fmaf(a.w, a.w, s);
    s = fmaf(b4.x, b4.x, s); s = fmaf(b4.y, b4.y, s);
    s = fmaf(b4.z, b4.z, s); s = fmaf(b4.w, b4.w, s);
    float tw = 2.f / fmaxf(EPSF, sqrtf(s));

    float bs = -1e38f;
    int bj = 0;
    #pragma unroll 4
    for (int jj = 0; jj < 128; ++jj) {
        int j = (jj << 3) + sub;
        float4 ca  = ((const float4*)s_cb)[j * 2];
        float4 cbv = ((const float4*)s_cb)[j * 2 + 1];
        float dot = 0.f;
        dot = fmaf(ca.x,  a.x,  dot);
        dot = fmaf(ca.y,  a.y,  dot);
        dot = fmaf(ca.z,  a.z,  dot);
        dot = fmaf(ca.w,  a.w,  dot);
        dot = fmaf(cbv.x, b4.x, dot);
        dot = fmaf(cbv.y, b4.y, dot);
        dot = fmaf(cbv.z, b4.z, dot);
        dot = fmaf(cbv.w, b4.w, dot);
        float sc = fmaf(dot, tw, -s_c2[j]);
        if (sc > bs || (sc == bs && j < bj)) { bs = sc; bj = j; }
    }
    #pragma unroll
    for (int m = 1; m <= 4; m <<= 1) {
        float os = __shfl_xor(bs, m, 64);
        int   oj = __shfl_xor(bj, m, 64);
        bool take = (os > bs) || (os == bs && oj < bj);
        bs = take ? os : bs;
        bj = take ? oj : bj;
    }

    float lsum = 0.f;
    if (sub == 0) {
        const float* q = cb + (size_t)bj * CD_;
        float d0 = a.x  - q[0]; lsum = fmaf(d0, d0, lsum);
        float d1 = a.y  - q[1]; lsum = fmaf(d1, d1, lsum);
        float d2 = a.z  - q[2]; lsum = fmaf(d2, d2, lsum);
        float d3 = a.w  - q[3]; lsum = fmaf(d3, d3, lsum);
        float d4 = b4.x - q[4]; lsum = fmaf(d4, d4, lsum);
        float d5 = b4.y - q[5]; lsum = fmaf(d5, d5, lsum);
        float d6 = b4.z - q[6]; lsum = fmaf(d6, d6, lsum);
        float d7 = b4.w - q[7]; lsum = fmaf(d7, d7, lsum);
    }
    lsum += __shfl_xor(lsum, 1, 64);
    lsum += __shfl_xor(lsum, 2, 64);
    lsum += __shfl_xor(lsum, 4, 64);
    lsum += __shfl_xor(lsum, 8, 64);
    lsum += __shfl_xor(lsum, 16, 64);
    lsum += __shfl_xor(lsum, 32, 64);
    if (lane == 0) s_loss[wid] = lsum;

    if (sub == 0) {
        dout[IDX_OFF + row] = (float)bj;
        idx_out[row] = bj;
    }
    __syncthreads();
    if (t == 0) {
        float tot = s_loss[0] + s_loss[1] + s_loss[2] + s_loss[3];
        float v = tot * (1.f / 32768.f);
        int bt = row >> 12;
        atomicAdd(dout + COMMIT_OFF + bt, v);
        atomicAdd(dout + CBLOSS_OFF + bt, v);
    }
}

// ---------------------------------------------------------------------------
// Out projection (round-5 verbatim, bit-exact)
// ---------------------------------------------------------------------------
__global__ __launch_bounds__(256)
void vq_out(const float* __restrict__ cb, const float* __restrict__ ws,
            const float* __restrict__ out_b, const int* __restrict__ idx,
            float* __restrict__ out) {
    int t = threadIdx.x;
    int lane = t & 63;
    int wv = (blockIdx.x << 2) + (t >> 6);  // 0..4095
    const float* ow = ws + WS_OUTW;

    float4 ob[4];
    #pragma unroll
    for (int k = 0; k < 4; ++k)
        ob[k] = *(const float4*)(out_b + (k << 8) + (lane << 2));

    for (int it = 0; it < 4; ++it) {
        int bi = wv + (it << 12);
        int row0 = bi << 2;

        float zq[4][CD_];
        #pragma unroll
        for (int r = 0; r < 4; ++r) {
            int j = idx[row0 + r];
            #pragma unroll
            for (int c = 0; c < CD_; ++c) zq[r][c] = cb[j * CD_ + c];
        }

        #pragma unroll
        for (int k = 0; k < 4; ++k) {
            float4 a0 = ob[k], a1 = ob[k], a2 = ob[k], a3 = ob[k];
            #pragma unroll
            for (int c = 0; c < CD_; ++c) {
                float4 w4 = *(const float4*)(ow + c * D_ + (k << 8) + (lane << 2));
                a0.x = fmaf(zq[0][c], w4.x, a0.x); a0.y = fmaf(zq[0][c], w4.y, a0.y);
                a0.z = fmaf(zq[0][c], w4.z, a0.z); a0.w = fmaf(zq[0][c], w4.w, a0.w);
                a1.x = fmaf(zq[1][c], w4.x, a1.x); a1.y = fmaf(zq[1][c], w4.y, a1.y);
                a1.z = fmaf(zq[1][c], w4.z, a1.z); a1.w = fmaf(zq[1][c], w4.w, a1.w);
                a2.x = fmaf(zq[2][c], w4.x, a2.x); a2.y = fmaf(zq[2][c], w4.y, a2.y);
                a2.z = fmaf(zq[2][c], w4.z, a2.z); a2.w = fmaf(zq[2][c], w4.w, a2.w);
                a3.x = fmaf(zq[3][c], w4.x, a3.x); a3.y = fmaf(zq[3][c], w4.y, a3.y);
                a3.z = fmaf(zq[3][c], w4.z, a3.z); a3.w = fmaf(zq[3][c], w4.w, a3.w);
            }
            size_t base = (size_t)row0 * D_ + (k << 8) + (lane << 2);
            *(float4*)(out + base)            = a0;
            *(float4*)(out + base + D_)       = a1;
            *(float4*)(out + base + 2 * D_)   = a2;
            *(float4*)(out + base + 3 * D_)   = a3;
        }
    }
}

extern "C" void kernel_launch(void* const* d_in, const int* in_sizes, int n_in,
                              void* d_out, int out_size, void* d_ws, size_t ws_size,
                              hipStream_t stream) {
    const float* z     = (const float*)d_in[0];
    const float* in_v  = (const float*)d_in[1];
    const float* in_g  = (const float*)d_in[2];
    const float* in_b  = (const float*)d_in[3];
    const float* out_v = (const float*)d_in[4];
    const float* out_g = (const float*)d_in[5];
    const float* out_b = (const float*)d_in[6];
    const float* cb    = (const float*)d_in[7];
    float* dout = (float*)d_out;
    float* ws   = (float*)d_ws;
    int* idxp   = (int*)(ws + WS_IDX);

    vq_prep<<<24, 256, 0, stream>>>(in_v, in_g, out_v, out_g, cb, ws, dout);
    vq_ze<<<2048, 256, 0, stream>>>(z, in_b, ws, dout);
    vq_scan<<<2048, 256, 0, stream>>>(dout + ZE_OFF, cb, ws, dout, idxp);
    vq_out<<<1024, 256, 0, stream>>>(cb, ws, out_b, idxp, dout + OUT_OFF);
}

// Round 9
// 178.571 us; speedup vs baseline: 1.1122x; 1.0213x over previous
//
#include <hip/hip_runtime.h>

#define B_    16
#define T_    4096
#define D_    1024
#define CD_   8
#define CS_   1024
#define NROWS 65536
#define EPSF  1e-12f

// ---- d_out float offsets (outputs concatenated flat in return order) ----
#define OUT_OFF    0           // [16,4096,1024] = 67108864
#define COMMIT_OFF 67108864    // [16]
#define CBLOSS_OFF 67108880    // [16]
#define IDX_OFF    67108896    // [16,4096] as float
#define ZE_OFF     67174432    // [16,4096,8]

// ---- ws float offsets ----
#define WS_INWT 0        // in_wT   [8][1024]  (c-major)
#define WS_CBR  8192     // cbn_row [1024][8]  (row-major normalized codebook)
#define WS_OUTW 16384    // out_w   [8][1024]  (c-major)
#define WS_CN2  24576    // ||cbn_j||^2 [1024]
#define WS_IDX  25600    // indices as int [65536]

// DPP-based pairwise add: lane i += lane (dpp-selected). VALU-only (no DS).
// quad_perm [1,0,3,2] = 0xB1 (xor1), [2,3,0,1] = 0x4E (xor2),
// row_ror:4 = 0x124, row_ror:8 = 0x128.
template <int CTRL>
static __device__ __forceinline__ float dpp_add(float x) {
    int xi = __builtin_bit_cast(int, x);
    int yi = __builtin_amdgcn_update_dpp(xi, xi, CTRL, 0xF, 0xF, false);
    return x + __builtin_bit_cast(float, yi);
}

// ---------------------------------------------------------------------------
// Prep, 24 blocks x 256 (round-5 verbatim, bit-exact)
// ---------------------------------------------------------------------------
__global__ __launch_bounds__(256)
void vq_prep(const float* __restrict__ in_v, const float* __restrict__ in_g,
             const float* __restrict__ out_v, const float* __restrict__ out_g,
             const float* __restrict__ cb, float* __restrict__ ws,
             float* __restrict__ dout) {
    int t = threadIdx.x;
    int blk = blockIdx.x;

    if (blk < 16) {
        __shared__ float s_norm[CD_];
        int lane = t & 63;
        int wid = t >> 6;     // 0..3
        #pragma unroll
        for (int half = 0; half < 2; ++half) {
            int c = wid + half * 4;
            float s = 0.f;
            #pragma unroll
            for (int i = 0; i < D_ / 64; ++i) {
                float v = in_v[(size_t)(lane + 64 * i) * CD_ + c];
                s = fmaf(v, v, s);
            }
            #pragma unroll
            for (int m = 1; m <= 32; m <<= 1) s += __shfl_xor(s, m, 64);
            if (lane == 0) s_norm[c] = sqrtf(s);
        }
        __syncthreads();

        #pragma unroll
        for (int rep = 0; rep < 2; ++rep) {
            int idx = blk * 512 + rep * 256 + t;
            int c = idx >> 10, d = idx & (D_ - 1);
            ws[WS_INWT + idx] = in_g[c] * in_v[(size_t)d * CD_ + c] / fmaxf(EPSF, s_norm[c]);
        }

        if (blk == 0 && t < 32) dout[COMMIT_OFF + t] = 0.f;
    } else if (blk < 20) {
        int j = (blk - 16) * 256 + t;
        float v[CD_]; float s = 0.f;
        #pragma unroll
        for (int c = 0; c < CD_; ++c) { v[c] = cb[j * CD_ + c]; s = fmaf(v[c], v[c], s); }
        float n = fmaxf(EPSF, sqrtf(s));
        float n2 = 0.f;
        #pragma unroll
        for (int c = 0; c < CD_; ++c) {
            float q = v[c] / n;
            ws[WS_CBR + j * CD_ + c] = q;
            n2 = fmaf(q, q, n2);
        }
        ws[WS_CN2 + j] = n2;
    } else {
        int d = (blk - 20) * 256 + t;
        float v[CD_]; float s = 0.f;
        #pragma unroll
        for (int c = 0; c < CD_; ++c) { v[c] = out_v[c * D_ + d]; s = fmaf(v[c], v[c], s); }
        float n = fmaxf(EPSF, sqrtf(s));
        float g = out_g[d];
        #pragma unroll
        for (int c = 0; c < CD_; ++c) ws[WS_OUTW + c * D_ + d] = g * v[c] / n;
    }
}

// ---------------------------------------------------------------------------
// Stage 1: z_e = z @ in_wT + in_b. Round-5 structure (2 rows/wave-iter), but
// the 6-level DS-shuffle butterfly is replaced by 4 DPP adds (VALU) + 2
// shuffles. Pairings reproduce the exact xor-tree bracketing on the storing
// lanes (0,1) -> z_e bit-identical.
// ---------------------------------------------------------------------------
__global__ __launch_bounds__(256)
void vq_ze(const float* __restrict__ z, const float* __restrict__ in_b,
           const float* __restrict__ ws, float* __restrict__ dout) {
    __shared__ float lds[CD_ * D_];  // in_wT, 32 KB
    int t = threadIdx.x;
    #pragma unroll
    for (int i = 0; i < 8; ++i)
        ((float4*)lds)[i * 256 + t] = ((const float4*)ws)[i * 256 + t];
    __syncthreads();

    int lane = t & 63;
    int wv = (blockIdx.x << 2) + (t >> 6);  // 0..8191

    float bia[CD_];
    #pragma unroll
    for (int c = 0; c < CD_; ++c) bia[c] = in_b[c];

    for (int it = 0; it < 4; ++it) {
        int bi = wv + (it << 13);   // 0..32767
        int row0 = bi << 1;         // 2 consecutive rows

        float ze[2][CD_];
        #pragma unroll
        for (int r = 0; r < 2; ++r)
            #pragma unroll
            for (int c = 0; c < CD_; ++c) ze[r][c] = 0.f;

        #pragma unroll
        for (int k = 0; k < 4; ++k) {
            float4 zv0 = *(const float4*)(z + (size_t)(row0)     * D_ + (k << 8) + (lane << 2));
            float4 zv1 = *(const float4*)(z + (size_t)(row0 + 1) * D_ + (k << 8) + (lane << 2));
            #pragma unroll
            for (int c = 0; c < CD_; ++c) {
                float4 w4 = *(const float4*)(lds + c * D_ + (k << 8) + (lane << 2));
                ze[0][c] = fmaf(zv0.x, w4.x, ze[0][c]);
                ze[0][c] = fmaf(zv0.y, w4.y, ze[0][c]);
                ze[0][c] = fmaf(zv0.z, w4.z, ze[0][c]);
                ze[0][c] = fmaf(zv0.w, w4.w, ze[0][c]);
                ze[1][c] = fmaf(zv1.x, w4.x, ze[1][c]);
                ze[1][c] = fmaf(zv1.y, w4.y, ze[1][c]);
                ze[1][c] = fmaf(zv1.z, w4.z, ze[1][c]);
                ze[1][c] = fmaf(zv1.w, w4.w, ze[1][c]);
            }
        }

        // Reduction: levels 1,2,4,8 via DPP (VALU), levels 16,32 via shuffles.
        // Bit-exact vs the xor butterfly on lanes (l%16)<4 (we store from 0,1).
        #pragma unroll
        for (int r = 0; r < 2; ++r) {
            #pragma unroll
            for (int c = 0; c < CD_; ++c) {
                float v = ze[r][c];
                v = dpp_add<0xB1>(v);    // quad_perm [1,0,3,2]  : + lane^1
                v = dpp_add<0x4E>(v);    // quad_perm [2,3,0,1]  : + lane^2
                v = dpp_add<0x124>(v);   // row_ror:4            : + lane+4
                v = dpp_add<0x128>(v);   // row_ror:8            : + lane+8
                v += __shfl_xor(v, 16, 64);
                v += __shfl_xor(v, 32, 64);
                ze[r][c] = v + bia[c];
            }
        }

        if (lane == 0) {
            *(float4*)(dout + ZE_OFF + (size_t)row0 * CD_) =
                make_float4(ze[0][0], ze[0][1], ze[0][2], ze[0][3]);
            *(float4*)(dout + ZE_OFF + (size_t)row0 * CD_ + 4) =
                make_float4(ze[0][4], ze[0][5], ze[0][6], ze[0][7]);
        }
        if (lane == 1) {
            *(float4*)(dout + ZE_OFF + (size_t)(row0 + 1) * CD_) =
                make_float4(ze[1][0], ze[1][1], ze[1][2], ze[1][3]);
            *(float4*)(dout + ZE_OFF + (size_t)(row0 + 1) * CD_ + 4) =
                make_float4(ze[1][4], ze[1][5], ze[1][6], ze[1][7]);
        }
    }
}

// ---------------------------------------------------------------------------
// Stage 2: scan (round-5 verbatim, bit-exact). 2048 blocks x 256.
// ---------------------------------------------------------------------------
__global__ __launch_bounds__(256)
void vq_scan(const float* __restrict__ ze_in, const float* __restrict__ cb,
             const float* __restrict__ ws, float* __restrict__ dout,
             int* __restrict__ idx_out) {
    __shared__ float s_cb[CS_ * CD_];  // 32 KB
    __shared__ float s_c2[CS_];        // 4 KB
    __shared__ float s_loss[4];
    int t = threadIdx.x;
    #pragma unroll
    for (int i = 0; i < 8; ++i)
        ((float4*)s_cb)[i * 256 + t] = ((const float4*)(ws + WS_CBR))[i * 256 + t];
    ((float4*)s_c2)[t] = ((const float4*)(ws + WS_CN2))[t];
    __syncthreads();

    int lane = t & 63;
    int wid = t >> 6;
    int r = t >> 3;            // 0..31 local row
    int sub = t & 7;
    int row = blockIdx.x * 32 + r;

    float4 a  = *(const float4*)(ze_in + (size_t)row * CD_);
    float4 b4 = *(const float4*)(ze_in + (size_t)row * CD_ + 4);

    float s = 0.f;
    s = fmaf(a.x, a.x, s);   s = fmaf(a.y, a.y, s);
    s = fmaf(a.z, a.z, s);   s = fmaf(a.w, a.w, s);
    s = fmaf(b4.x, b4.x, s); s = fmaf(b4.y, b4.y, s);
    s = fmaf(b4.z, b4.z, s); s = fmaf(b4.w, b4.w, s);
    float tw = 2.f / fmaxf(EPSF, sqrtf(s));

    float bs = -1e38f;
    int bj = 0;
    #pragma unroll 4
    for (int jj = 0; jj < 128; ++jj) {
        int j = (jj << 3) + sub;
        float4 ca  = ((const float4*)s_cb)[j * 2];
        float4 cbv = ((const float4*)s_cb)[j * 2 + 1];
        float dot = 0.f;
        dot = fmaf(ca.x,  a.x,  dot);
        dot = fmaf(ca.y,  a.y,  dot);
        dot = fmaf(ca.z,  a.z,  dot);
        dot = fmaf(ca.w,  a.w,  dot);
        dot = fmaf(cbv.x, b4.x, dot);
        dot = fmaf(cbv.y, b4.y, dot);
        dot = fmaf(cbv.z, b4.z, dot);
        dot = fmaf(cbv.w, b4.w, dot);
        float sc = fmaf(dot, tw, -s_c2[j]);
        if (sc > bs || (sc == bs && j < bj)) { bs = sc; bj = j; }
    }
    #pragma unroll
    for (int m = 1; m <= 4; m <<= 1) {
        float os = __shfl_xor(bs, m, 64);
        int   oj = __shfl_xor(bj, m, 64);
        bool take = (os > bs) || (os == bs && oj < bj);
        bs = take ? os : bs;
        bj = take ? oj : bj;
    }

    float lsum = 0.f;
    if (sub == 0) {
        const float* q = cb + (size_t)bj * CD_;
        float d0 = a.x  - q[0]; lsum = fmaf(d0, d0, lsum);
        float d1 = a.y  - q[1]; lsum = fmaf(d1, d1, lsum);
        float d2 = a.z  - q[2]; lsum = fmaf(d2, d2, lsum);
        float d3 = a.w  - q[3]; lsum = fmaf(d3, d3, lsum);
        float d4 = b4.x - q[4]; lsum = fmaf(d4, d4, lsum);
        float d5 = b4.y - q[5]; lsum = fmaf(d5, d5, lsum);
        float d6 = b4.z - q[6]; lsum = fmaf(d6, d6, lsum);
        float d7 = b4.w - q[7]; lsum = fmaf(d7, d7, lsum);
    }
    lsum += __shfl_xor(lsum, 1, 64);
    lsum += __shfl_xor(lsum, 2, 64);
    lsum += __shfl_xor(lsum, 4, 64);
    lsum += __shfl_xor(lsum, 8, 64);
    lsum += __shfl_xor(lsum, 16, 64);
    lsum += __shfl_xor(lsum, 32, 64);
    if (lane == 0) s_loss[wid] = lsum;

    if (sub == 0) {
        dout[IDX_OFF + row] = (float)bj;
        idx_out[row] = bj;
    }
    __syncthreads();
    if (t == 0) {
        float tot = s_loss[0] + s_loss[1] + s_loss[2] + s_loss[3];
        float v = tot * (1.f / 32768.f);
        int bt = row >> 12;
        atomicAdd(dout + COMMIT_OFF + bt, v);
        atomicAdd(dout + CBLOSS_OFF + bt, v);
    }
}

// ---------------------------------------------------------------------------
// Out projection (round-5 verbatim, bit-exact)
// ---------------------------------------------------------------------------
__global__ __launch_bounds__(256)
void vq_out(const float* __restrict__ cb, const float* __restrict__ ws,
            const float* __restrict__ out_b, const int* __restrict__ idx,
            float* __restrict__ out) {
    int t = threadIdx.x;
    int lane = t & 63;
    int wv = (blockIdx.x << 2) + (t >> 6);  // 0..4095
    const float* ow = ws + WS_OUTW;

    float4 ob[4];
    #pragma unroll
    for (int k = 0; k < 4; ++k)
        ob[k] = *(const float4*)(out_b + (k << 8) + (lane << 2));

    for (int it = 0; it < 4; ++it) {
        int bi = wv + (it << 12);
        int row0 = bi << 2;

        float zq[4][CD_];
        #pragma unroll
        for (int r = 0; r < 4; ++r) {
            int j = idx[row0 + r];
            #pragma unroll
            for (int c = 0; c < CD_; ++c) zq[r][c] = cb[j * CD_ + c];
        }

        #pragma unroll
        for (int k = 0; k < 4; ++k) {
            float4 a0 = ob[k], a1 = ob[k], a2 = ob[k], a3 = ob[k];
            #pragma unroll
            for (int c = 0; c < CD_; ++c) {
                float4 w4 = *(const float4*)(ow + c * D_ + (k << 8) + (lane << 2));
                a0.x = fmaf(zq[0][c], w4.x, a0.x); a0.y = fmaf(zq[0][c], w4.y, a0.y);
                a0.z = fmaf(zq[0][c], w4.z, a0.z); a0.w = fmaf(zq[0][c], w4.w, a0.w);
                a1.x = fmaf(zq[1][c], w4.x, a1.x); a1.y = fmaf(zq[1][c], w4.y, a1.y);
                a1.z = fmaf(zq[1][c], w4.z, a1.z); a1.w = fmaf(zq[1][c], w4.w, a1.w);
                a2.x = fmaf(zq[2][c], w4.x, a2.x); a2.y = fmaf(zq[2][c], w4.y, a2.y);
                a2.z = fmaf(zq[2][c], w4.z, a2.z); a2.w = fmaf(zq[2][c], w4.w, a2.w);
                a3.x = fmaf(zq[3][c], w4.x, a3.x); a3.y = fmaf(zq[3][c], w4.y, a3.y);
                a3.z = fmaf(zq[3][c], w4.z, a3.z); a3.w = fmaf(zq[3][c], w4.w, a3.w);
            }
            size_t base = (size_t)row0 * D_ + (k << 8) + (lane << 2);
            *(float4*)(out + base)            = a0;
            *(float4*)(out + base + D_)       = a1;
            *(float4*)(out + base + 2 * D_)   = a2;
            *(float4*)(out + base + 3 * D_)   = a3;
        }
    }
}

extern "C" void kernel_launch(void* const* d_in, const int* in_sizes, int n_in,
                              void* d_out, int out_size, void* d_ws, size_t ws_size,
                              hipStream_t stream) {
    const float* z     = (const float*)d_in[0];
    const float* in_v  = (const float*)d_in[1];
    const float* in_g  = (const float*)d_in[2];
    const float* in_b  = (const float*)d_in[3];
    const float* out_v = (const float*)d_in[4];
    const float* out_g = (const float*)d_in[5];
    const float* out_b = (const float*)d_in[6];
    const float* cb    = (const float*)d_in[7];
    float* dout = (float*)d_out;
    float* ws   = (float*)d_ws;
    int* idxp   = (int*)(ws + WS_IDX);

    vq_prep<<<24, 256, 0, stream>>>(in_v, in_g, out_v, out_g, cb, ws, dout);
    vq_ze<<<2048, 256, 0, stream>>>(z, in_b, ws, dout);
    vq_scan<<<2048, 256, 0, stream>>>(dout + ZE_OFF, cb, ws, dout, idxp);
    vq_out<<<1024, 256, 0, stream>>>(cb, ws, out_b, idxp, dout + OUT_OFF);
}

// Round 10
// 178.299 us; speedup vs baseline: 1.1139x; 1.0015x over previous
//
#include <hip/hip_runtime.h>

#define B_    16
#define T_    4096
#define D_    1024
#define CD_   8
#define CS_   1024
#define NROWS 65536
#define EPSF  1e-12f

// ---- d_out float offsets ----
#define OUT_OFF    0
#define COMMIT_OFF 67108864
#define CBLOSS_OFF 67108880
#define IDX_OFF    67108896
#define ZE_OFF     67174432

// ---- ws float offsets ----
#define WS_INWT 0
#define WS_CBR  8192
#define WS_OUTW 16384
#define WS_CN2  24576
#define WS_IDX  25600

template <int CTRL>
static __device__ __forceinline__ float dpp_add(float x) {
    int xi = __builtin_bit_cast(int, x);
    int yi = __builtin_amdgcn_update_dpp(xi, xi, CTRL, 0xF, 0xF, false);
    return x + __builtin_bit_cast(float, yi);
}

// ---------------------------------------------------------------------------
// Prep, 24 blocks x 256 (round-5 verbatim)
// ---------------------------------------------------------------------------
__global__ __launch_bounds__(256)
void vq_prep(const float* __restrict__ in_v, const float* __restrict__ in_g,
             const float* __restrict__ out_v, const float* __restrict__ out_g,
             const float* __restrict__ cb, float* __restrict__ ws,
             float* __restrict__ dout) {
    int t = threadIdx.x;
    int blk = blockIdx.x;

    if (blk < 16) {
        __shared__ float s_norm[CD_];
        int lane = t & 63;
        int wid = t >> 6;
        #pragma unroll
        for (int half = 0; half < 2; ++half) {
            int c = wid + half * 4;
            float s = 0.f;
            #pragma unroll
            for (int i = 0; i < D_ / 64; ++i) {
                float v = in_v[(size_t)(lane + 64 * i) * CD_ + c];
                s = fmaf(v, v, s);
            }
            #pragma unroll
            for (int m = 1; m <= 32; m <<= 1) s += __shfl_xor(s, m, 64);
            if (lane == 0) s_norm[c] = sqrtf(s);
        }
        __syncthreads();

        #pragma unroll
        for (int rep = 0; rep < 2; ++rep) {
            int idx = blk * 512 + rep * 256 + t;
            int c = idx >> 10, d = idx & (D_ - 1);
            ws[WS_INWT + idx] = in_g[c] * in_v[(size_t)d * CD_ + c] / fmaxf(EPSF, s_norm[c]);
        }

        if (blk == 0 && t < 32) dout[COMMIT_OFF + t] = 0.f;
    } else if (blk < 20) {
        int j = (blk - 16) * 256 + t;
        float v[CD_]; float s = 0.f;
        #pragma unroll
        for (int c = 0; c < CD_; ++c) { v[c] = cb[j * CD_ + c]; s = fmaf(v[c], v[c], s); }
        float n = fmaxf(EPSF, sqrtf(s));
        float n2 = 0.f;
        #pragma unroll
        for (int c = 0; c < CD_; ++c) {
            float q = v[c] / n;
            ws[WS_CBR + j * CD_ + c] = q;
            n2 = fmaf(q, q, n2);
        }
        ws[WS_CN2 + j] = n2;
    } else {
        int d = (blk - 20) * 256 + t;
        float v[CD_]; float s = 0.f;
        #pragma unroll
        for (int c = 0; c < CD_; ++c) { v[c] = out_v[c * D_ + d]; s = fmaf(v[c], v[c], s); }
        float n = fmaxf(EPSF, sqrtf(s));
        float g = out_g[d];
        #pragma unroll
        for (int c = 0; c < CD_; ++c) ws[WS_OUTW + c * D_ + d] = g * v[c] / n;
    }
}

// ---------------------------------------------------------------------------
// Stage 1: z_e GEMV. 512 thr x 1024 blocks (24 waves/CU). Even/odd float2
// accumulators -> v_pk_fma_f32-packable pairs; DPP+shfl reduction.
// ---------------------------------------------------------------------------
__global__ __launch_bounds__(512)
void vq_ze(const float* __restrict__ z, const float* __restrict__ in_b,
           const float* __restrict__ ws, float* __restrict__ dout) {
    __shared__ float lds[CD_ * D_];  // in_wT, 32 KB
    int t = threadIdx.x;
    #pragma unroll
    for (int i = 0; i < 4; ++i)
        ((float4*)lds)[i * 512 + t] = ((const float4*)ws)[i * 512 + t];
    __syncthreads();

    int lane = t & 63;
    int wv = (blockIdx.x << 3) + (t >> 6);  // 0..8191

    float bia[CD_];
    #pragma unroll
    for (int c = 0; c < CD_; ++c) bia[c] = in_b[c];

    #pragma unroll
    for (int it = 0; it < 4; ++it) {
        int bi = wv + (it << 13);   // 0..32767
        int row0 = bi << 1;

        float2 acc[2][CD_];
        #pragma unroll
        for (int r = 0; r < 2; ++r)
            #pragma unroll
            for (int c = 0; c < CD_; ++c) acc[r][c] = make_float2(0.f, 0.f);

        #pragma unroll
        for (int k = 0; k < 4; ++k) {
            float4 zv0 = *(const float4*)(z + (size_t)(row0)     * D_ + (k << 8) + (lane << 2));
            float4 zv1 = *(const float4*)(z + (size_t)(row0 + 1) * D_ + (k << 8) + (lane << 2));
            #pragma unroll
            for (int c = 0; c < CD_; ++c) {
                float4 w4 = *(const float4*)(lds + c * D_ + (k << 8) + (lane << 2));
                acc[0][c].x = fmaf(zv0.x, w4.x, acc[0][c].x);
                acc[0][c].y = fmaf(zv0.y, w4.y, acc[0][c].y);
                acc[0][c].x = fmaf(zv0.z, w4.z, acc[0][c].x);
                acc[0][c].y = fmaf(zv0.w, w4.w, acc[0][c].y);
                acc[1][c].x = fmaf(zv1.x, w4.x, acc[1][c].x);
                acc[1][c].y = fmaf(zv1.y, w4.y, acc[1][c].y);
                acc[1][c].x = fmaf(zv1.z, w4.z, acc[1][c].x);
                acc[1][c].y = fmaf(zv1.w, w4.w, acc[1][c].y);
            }
        }

        float ze[2][CD_];
        #pragma unroll
        for (int r = 0; r < 2; ++r) {
            #pragma unroll
            for (int c = 0; c < CD_; ++c) {
                float v = acc[r][c].x + acc[r][c].y;
                v = dpp_add<0xB1>(v);    // + lane^1
                v = dpp_add<0x4E>(v);    // + lane^2
                v = dpp_add<0x124>(v);   // + lane+4 (row_ror:4)
                v = dpp_add<0x128>(v);   // + lane+8 (row_ror:8)
                v += __shfl_xor(v, 16, 64);
                v += __shfl_xor(v, 32, 64);
                ze[r][c] = v + bia[c];
            }
        }

        if (lane == 0) {
            *(float4*)(dout + ZE_OFF + (size_t)row0 * CD_) =
                make_float4(ze[0][0], ze[0][1], ze[0][2], ze[0][3]);
            *(float4*)(dout + ZE_OFF + (size_t)row0 * CD_ + 4) =
                make_float4(ze[0][4], ze[0][5], ze[0][6], ze[0][7]);
        }
        if (lane == 1) {
            *(float4*)(dout + ZE_OFF + (size_t)(row0 + 1) * CD_) =
                make_float4(ze[1][0], ze[1][1], ze[1][2], ze[1][3]);
            *(float4*)(dout + ZE_OFF + (size_t)(row0 + 1) * CD_ + 4) =
                make_float4(ze[1][4], ze[1][5], ze[1][6], ze[1][7]);
        }
    }
}

// ---------------------------------------------------------------------------
// Stage 2: scan. Round-5 structure; dot split into even/odd float2 partials
// (v_pk_fma_f32-packable). Tie policy unchanged (strict >, smaller j).
// ---------------------------------------------------------------------------
__global__ __launch_bounds__(256)
void vq_scan(const float* __restrict__ ze_in, const float* __restrict__ cb,
             const float* __restrict__ ws, float* __restrict__ dout,
             int* __restrict__ idx_out) {
    __shared__ float s_cb[CS_ * CD_];  // 32 KB
    __shared__ float s_c2[CS_];        // 4 KB
    __shared__ float s_loss[4];
    int t = threadIdx.x;
    #pragma unroll
    for (int i = 0; i < 8; ++i)
        ((float4*)s_cb)[i * 256 + t] = ((const float4*)(ws + WS_CBR))[i * 256 + t];
    ((float4*)s_c2)[t] = ((const float4*)(ws + WS_CN2))[t];
    __syncthreads();

    int lane = t & 63;
    int wid = t >> 6;
    int r = t >> 3;
    int sub = t & 7;
    int row = blockIdx.x * 32 + r;

    float4 a  = *(const float4*)(ze_in + (size_t)row * CD_);
    float4 b4 = *(const float4*)(ze_in + (size_t)row * CD_ + 4);

    float s = 0.f;
    s = fmaf(a.x, a.x, s);   s = fmaf(a.y, a.y, s);
    s = fmaf(a.z, a.z, s);   s = fmaf(a.w, a.w, s);
    s = fmaf(b4.x, b4.x, s); s = fmaf(b4.y, b4.y, s);
    s = fmaf(b4.z, b4.z, s); s = fmaf(b4.w, b4.w, s);
    float tw = 2.f / fmaxf(EPSF, sqrtf(s));

    float bs = -1e38f;
    int bj = 0;
    #pragma unroll 4
    for (int jj = 0; jj < 128; ++jj) {
        int j = (jj << 3) + sub;
        float4 ca  = ((const float4*)s_cb)[j * 2];
        float4 cbv = ((const float4*)s_cb)[j * 2 + 1];
        float2 dp = make_float2(0.f, 0.f);
        dp.x = fmaf(ca.x,  a.x,  dp.x);
        dp.y = fmaf(ca.y,  a.y,  dp.y);
        dp.x = fmaf(ca.z,  a.z,  dp.x);
        dp.y = fmaf(ca.w,  a.w,  dp.y);
        dp.x = fmaf(cbv.x, b4.x, dp.x);
        dp.y = fmaf(cbv.y, b4.y, dp.y);
        dp.x = fmaf(cbv.z, b4.z, dp.x);
        dp.y = fmaf(cbv.w, b4.w, dp.y);
        float dot = dp.x + dp.y;
        float sc = fmaf(dot, tw, -s_c2[j]);
        if (sc > bs || (sc == bs && j < bj)) { bs = sc; bj = j; }
    }
    #pragma unroll
    for (int m = 1; m <= 4; m <<= 1) {
        float os = __shfl_xor(bs, m, 64);
        int   oj = __shfl_xor(bj, m, 64);
        bool take = (os > bs) || (os == bs && oj < bj);
        bs = take ? os : bs;
        bj = take ? oj : bj;
    }

    float lsum = 0.f;
    if (sub == 0) {
        const float* q = cb + (size_t)bj * CD_;
        float d0 = a.x  - q[0]; lsum = fmaf(d0, d0, lsum);
        float d1 = a.y  - q[1]; lsum = fmaf(d1, d1, lsum);
        float d2 = a.z  - q[2]; lsum = fmaf(d2, d2, lsum);
        float d3 = a.w  - q[3]; lsum = fmaf(d3, d3, lsum);
        float d4 = b4.x - q[4]; lsum = fmaf(d4, d4, lsum);
        float d5 = b4.y - q[5]; lsum = fmaf(d5, d5, lsum);
        float d6 = b4.z - q[6]; lsum = fmaf(d6, d6, lsum);
        float d7 = b4.w - q[7]; lsum = fmaf(d7, d7, lsum);
    }
    lsum += __shfl_xor(lsum, 1, 64);
    lsum += __shfl_xor(lsum, 2, 64);
    lsum += __shfl_xor(lsum, 4, 64);
    lsum += __shfl_xor(lsum, 8, 64);
    lsum += __shfl_xor(lsum, 16, 64);
    lsum += __shfl_xor(lsum, 32, 64);
    if (lane == 0) s_loss[wid] = lsum;

    if (sub == 0) {
        dout[IDX_OFF + row] = (float)bj;
        idx_out[row] = bj;
    }
    __syncthreads();
    if (t == 0) {
        float tot = s_loss[0] + s_loss[1] + s_loss[2] + s_loss[3];
        float v = tot * (1.f / 32768.f);
        int bt = row >> 12;
        atomicAdd(dout + COMMIT_OFF + bt, v);
        atomicAdd(dout + CBLOSS_OFF + bt, v);
    }
}

// ---------------------------------------------------------------------------
// Out projection (round-5 verbatim)
// ---------------------------------------------------------------------------
__global__ __launch_bounds__(256)
void vq_out(const float* __restrict__ cb, const float* __restrict__ ws,
            const float* __restrict__ out_b, const int* __restrict__ idx,
            float* __restrict__ out) {
    int t = threadIdx.x;
    int lane = t & 63;
    int wv = (blockIdx.x << 2) + (t >> 6);
    const float* ow = ws + WS_OUTW;

    float4 ob[4];
    #pragma unroll
    for (int k = 0; k < 4; ++k)
        ob[k] = *(const float4*)(out_b + (k << 8) + (lane << 2));

    for (int it = 0; it < 4; ++it) {
        int bi = wv + (it << 12);
        int row0 = bi << 2;

        float zq[4][CD_];
        #pragma unroll
        for (int r = 0; r < 4; ++r) {
            int j = idx[row0 + r];
            #pragma unroll
            for (int c = 0; c < CD_; ++c) zq[r][c] = cb[j * CD_ + c];
        }

        #pragma unroll
        for (int k = 0; k < 4; ++k) {
            float4 a0 = ob[k], a1 = ob[k], a2 = ob[k], a3 = ob[k];
            #pragma unroll
            for (int c = 0; c < CD_; ++c) {
                float4 w4 = *(const float4*)(ow + c * D_ + (k << 8) + (lane << 2));
                a0.x = fmaf(zq[0][c], w4.x, a0.x); a0.y = fmaf(zq[0][c], w4.y, a0.y);
                a0.z = fmaf(zq[0][c], w4.z, a0.z); a0.w = fmaf(zq[0][c], w4.w, a0.w);
                a1.x = fmaf(zq[1][c], w4.x, a1.x); a1.y = fmaf(zq[1][c], w4.y, a1.y);
                a1.z = fmaf(zq[1][c], w4.z, a1.z); a1.w = fmaf(zq[1][c], w4.w, a1.w);
                a2.x = fmaf(zq[2][c], w4.x, a2.x); a2.y = fmaf(zq[2][c], w4.y, a2.y);
                a2.z = fmaf(zq[2][c], w4.z, a2.z); a2.w = fmaf(zq[2][c], w4.w, a2.w);
                a3.x = fmaf(zq[3][c], w4.x, a3.x); a3.y = fmaf(zq[3][c], w4.y, a3.y);
                a3.z = fmaf(zq[3][c], w4.z, a3.z); a3.w = fmaf(zq[3][c], w4.w, a3.w);
            }
            size_t base = (size_t)row0 * D_ + (k << 8) + (lane << 2);
            *(float4*)(out + base)            = a0;
            *(float4*)(out + base + D_)       = a1;
            *(float4*)(out + base + 2 * D_)   = a2;
            *(float4*)(out + base + 3 * D_)   = a3;
        }
    }
}

extern "C" void kernel_launch(void* const* d_in, const int* in_sizes, int n_in,
                              void* d_out, int out_size, void* d_ws, size_t ws_size,
                              hipStream_t stream) {
    const float* z     = (const float*)d_in[0];
    const float* in_v  = (const float*)d_in[1];
    const float* in_g  = (const float*)d_in[2];
    const float* in_b  = (const float*)d_in[3];
    const float* out_v = (const float*)d_in[4];
    const float* out_g = (const float*)d_in[5];
    const float* out_b = (const float*)d_in[6];
    const float* cb    = (const float*)d_in[7];
    float* dout = (float*)d_out;
    float* ws   = (float*)d_ws;
    int* idxp   = (int*)(ws + WS_IDX);

    vq_prep<<<24, 256, 0, stream>>>(in_v, in_g, out_v, out_g, cb, ws, dout);
    vq_ze<<<1024, 512, 0, stream>>>(z, in_b, ws, dout);
    vq_scan<<<2048, 256, 0, stream>>>(dout + ZE_OFF, cb, ws, dout, idxp);
    vq_out<<<1024, 256, 0, stream>>>(cb, ws, out_b, idxp, dout + OUT_OFF);
}